// Round 15
// baseline (172.432 us; speedup 1.0000x reference)
//
#include <hip/hip_runtime.h>
#include <stdint.h>

typedef __bf16 bf16;
typedef __bf16 bf16x8 __attribute__((ext_vector_type(8)));
typedef __bf16 bf16x4 __attribute__((ext_vector_type(4)));
typedef _Float16 f16;
typedef f16 f16x8 __attribute__((ext_vector_type(8)));
typedef f16 f16x4 __attribute__((ext_vector_type(4)));
typedef float f32x16 __attribute__((ext_vector_type(16)));
typedef uint32_t u32x4 __attribute__((ext_vector_type(4)));

#define LQ    16384   // B*L total rows
#define CDIM  1024
#define DDIM  128
#define NSPLIT 4
#define QS 0.12751741f   // (1/sqrt(128)) * log2(e): folded into Q -> softmax uses exp2

static __device__ __forceinline__ uint32_t pkrtz(float a, float b) {
  return __builtin_bit_cast(uint32_t, __builtin_amdgcn_cvt_pkrtz(a, b));
}

// no-drain barrier: LDS visibility only; global loads stay in flight.
static __device__ __forceinline__ void lds_barrier() {
  asm volatile("s_waitcnt lgkmcnt(0)" ::: "memory");
  __builtin_amdgcn_s_barrier();
}

// async global->LDS, 16 B per lane; LDS dest = wave-uniform base + lane*16.
static __device__ __forceinline__ void gload_lds16(const void* g, void* l) {
  __builtin_amdgcn_global_load_lds(
      (__attribute__((address_space(1))) void*)g,
      (__attribute__((address_space(3))) void*)l, 16, 0, 0);
}

// ---------------- K0: Wt[3][128][1024] (bf16, Q rows prescaled) + bias_all[384]
__global__ void prep_kernel(const float* __restrict__ Wq, const float* __restrict__ Wk,
                            const float* __restrict__ Wv, const float* __restrict__ bq,
                            const float* __restrict__ bk, const float* __restrict__ bv,
                            bf16* __restrict__ Wt, float* __restrict__ bias_all) {
  int idx = blockIdx.x * 256 + threadIdx.x;      // 0 .. 3*131072
  int p = idx >> 17;
  int rem = idx & 131071;
  int k = rem >> 7, n = rem & 127;
  const float* W = (p == 0) ? Wq : (p == 1) ? Wk : Wv;
  float s = (p == 0) ? QS : 1.0f;
  Wt[(size_t)(p * 128 + n) * CDIM + k] = (bf16)(W[rem] * s);
  if (idx < 384) {
    int pp = idx >> 7, nn = idx & 127;
    const float* b = (pp == 0) ? bq : (pp == 1) ? bk : bv;
    bias_all[idx] = b[nn] * ((pp == 0) ? QS : 1.0f);
  }
}

// ---------------- K1: QKV GEMM (round-13/14 green body, unchanged) ----------
__global__ __launch_bounds__(512, 1) void qkv_gemm(
    const float* __restrict__ x, const bf16* __restrict__ Wt,
    const float* __restrict__ bias_all,
    bf16* __restrict__ Qw, bf16* __restrict__ Kw, f16* __restrict__ Vtw) {
  __shared__ bf16 As[2][64 * 64];    // [m][k] swizzled, 8 KB each
  __shared__ bf16 Bs[2][384 * 64];   // [proj*128+n][k] swizzled, 48 KB each
  const int t = threadIdx.x;
  const int w = t >> 6;
  const int lane = t & 63;
  const int l31 = lane & 31;
  const int hi = lane >> 5;
  const int m0 = blockIdx.x * 64;
  const int m_off = (w & 1) * 32;
  const int n_off = ((w >> 1) & 3) * 32;

  const f32x16 z16 = {0.f,0.f,0.f,0.f,0.f,0.f,0.f,0.f,0.f,0.f,0.f,0.f,0.f,0.f,0.f,0.f};
  f32x16 acc[3];
  acc[0] = z16; acc[1] = z16; acc[2] = z16;

  const int srow = t >> 3;
  const int g = t & 7;
  const int sgoff = (g ^ (srow & 7)) * 8;   // swizzled granule (write side)
  const int scol = g * 8;

  const int lrow = lane >> 3;                 // 0..7
  const int lgr = (lane & 7) ^ lrow;          // pre-swizzled source granule
  const bf16* bsrc = Wt + (size_t)(w * 48 + lrow) * CDIM + lgr * 8;

  float4 xc0, xc1, xn0, xn1;

  // ---- prologue: B(0) async; A(0) staged; xa(1) prefetched ----
#pragma unroll
  for (int c = 0; c < 6; c++)
    gload_lds16(bsrc + (size_t)c * 8 * CDIM, &Bs[0][(w * 48 + c * 8) * 64]);
  {
    const float* p = &x[(size_t)(m0 + srow) * CDIM + scol];
    float4 a0 = *(const float4*)p;
    float4 a1 = *(const float4*)(p + 4);
    bf16x8 v;
    v[0] = (bf16)a0.x; v[1] = (bf16)a0.y; v[2] = (bf16)a0.z; v[3] = (bf16)a0.w;
    v[4] = (bf16)a1.x; v[5] = (bf16)a1.y; v[6] = (bf16)a1.z; v[7] = (bf16)a1.w;
    *(bf16x8*)&As[0][srow * 64 + sgoff] = v;   // implicit vmcnt drains B(0) too
  }
  {
    const float* p = &x[(size_t)(m0 + srow) * CDIM + 64 + scol];
    xc0 = *(const float4*)p;
    xc1 = *(const float4*)(p + 4);
  }
  lds_barrier();   // bar(0)

  for (int kc = 0; kc < 16; kc++) {
    bf16* Ab = As[kc & 1];
    bf16* Bb = Bs[kc & 1];

    if (kc < 15) {
      const bf16* s = bsrc + (kc + 1) * 64;
      bf16* Bn = Bs[(kc + 1) & 1];
#pragma unroll
      for (int c = 0; c < 6; c++)
        gload_lds16(s + (size_t)c * 8 * CDIM, &Bn[(w * 48 + c * 8) * 64]);
      __builtin_amdgcn_sched_barrier(0);   // pin: B issued before xa(t+2)
      if (kc < 14) {
        const float* p = &x[(size_t)(m0 + srow) * CDIM + (kc + 2) * 64 + scol];
        xn0 = *(const float4*)p;
        xn1 = *(const float4*)(p + 4);
      }
    }

#pragma unroll
    for (int ks = 0; ks < 4; ks++) {
      const int rg = ((ks * 2 + hi) ^ (l31 & 7)) * 8;   // swizzled read granule
      bf16x8 af = *(const bf16x8*)&Ab[(m_off + l31) * 64 + rg];
#pragma unroll
      for (int p = 0; p < 3; p++) {
        bf16x8 bfr = *(const bf16x8*)&Bb[(p * 128 + n_off + l31) * 64 + rg];
        acc[p] = __builtin_amdgcn_mfma_f32_32x32x16_bf16(af, bfr, acc[p], 0, 0, 0);
      }
    }

    if (kc < 15) {
      bf16* An = As[(kc + 1) & 1];
      bf16x8 v;
      v[0] = (bf16)xc0.x; v[1] = (bf16)xc0.y; v[2] = (bf16)xc0.z; v[3] = (bf16)xc0.w;
      v[4] = (bf16)xc1.x; v[5] = (bf16)xc1.y; v[6] = (bf16)xc1.z; v[7] = (bf16)xc1.w;
      *(bf16x8*)&An[srow * 64 + sgoff] = v;
      __builtin_amdgcn_sched_barrier(0);
      if (kc < 14)
        asm volatile("s_waitcnt vmcnt(2)" ::: "memory");
      else
        asm volatile("s_waitcnt vmcnt(0)" ::: "memory");
      lds_barrier();   // bar(kc+1): A+B visible
      xc0 = xn0; xc1 = xn1;
    }
  }

  const int n = n_off + l31;
#pragma unroll
  for (int p = 0; p < 3; p++) {
    const float bias = bias_all[p * 128 + n];
    if (p < 2) {
      bf16* outp = (p == 0) ? Qw : Kw;
#pragma unroll
      for (int r = 0; r < 16; r++) {
        int m = m0 + m_off + (r & 3) + 8 * (r >> 2) + 4 * hi;
        outp[(size_t)m * DDIM + n] = (bf16)(acc[p][r] + bias);
      }
    } else {
#pragma unroll
      for (int gq = 0; gq < 4; gq++) {
        int mbase = m0 + m_off + 8 * gq + 4 * hi;
        f16x4 pv;
#pragma unroll
        for (int r = 0; r < 4; r++) pv[r] = (f16)(acc[p][gq * 4 + r] + bias);
        *(f16x4*)&Vtw[(size_t)n * LQ + mbase] = pv;
      }
    }
  }
}

// ---------------- K2: flash, 64 q-rows/wave on the round-14 template --------
// grid (64 q-blocks of 256 rows, 4 KV quarters) = 256 blocks = 1/CU, 4 waves,
// 1 wave/SIMD (launch_bounds 256,1; ~390 VGPR). Each kf/vf LDS read feeds 2
// MFMAs (nq=0,1) -> LDS reads/CU-tile HALVED (the measured binding pipe).
// Schedule, buffers, barriers: byte-for-byte the round-9..14 green template
// (2-buffer K/V, mid lds_barrier, end-of-body s_barrier race fix). The race
// that killed round 7 is structurally removed by the end barrier; round 8's
// triple-buffer rotation is NOT used.
__global__ __launch_bounds__(256, 1) void flash_kernel(
    const bf16* __restrict__ Qw, const bf16* __restrict__ Kw, const f16* __restrict__ Vtw,
    bf16* __restrict__ Opb, float* __restrict__ lp) {
  __shared__ bf16 Kl[2][64 * 136];    // [kv][d] pad 128->136
  __shared__ f16  Vl[2][128 * 72];    // [d][kv] pad 64->72

  const int t = threadIdx.x;
  const int w = t >> 6;
  const int lane = t & 63;
  const int l31 = lane & 31;
  const int hi = lane >> 5;
  // 256 blocks, bijective XCD chunk map (32 logical / XCD)
  const int lin = blockIdx.y * 64 + blockIdx.x;
  const int logical = ((lin & 7) << 5) + (lin >> 3);
  const int qb = logical & 63;        // 0..63 (256 q rows each)
  const int sp = logical >> 6;        // 0..3
  const int batch = qb >> 4;
  const int q0w = qb * 256 + w * 64;  // this wave's 64 q rows
  const int kv_base = batch * 4096 + sp * 1024;

  // Q fragments: qf{0,1}[ks], col q = q0w + nq*32 + l31
  bf16x8 qf0[8], qf1[8];
#pragma unroll
  for (int ks = 0; ks < 8; ks++) {
    qf0[ks] = *(const bf16x8*)&Qw[(size_t)(q0w + l31) * DDIM + ks * 16 + hi * 8];
    qf1[ks] = *(const bf16x8*)&Qw[(size_t)(q0w + 32 + l31) * DDIM + ks * 16 + hi * 8];
  }

  const f32x16 z16 = {0.f,0.f,0.f,0.f,0.f,0.f,0.f,0.f,0.f,0.f,0.f,0.f,0.f,0.f,0.f,0.f};
  f32x16 o0[4], o1[4];                // O: q = q0w+nq*32+crow(r,hi), d = dt*32+l31
#pragma unroll
  for (int dt = 0; dt < 4; dt++) { o0[dt] = z16; o1[dt] = z16; }
  f32x16 li0 = z16, li1 = z16;        // row sums

  f16x8 ones;
#pragma unroll
  for (int i = 0; i < 8; i++) ones[i] = (f16)1.f;

  // staging geometry (256 thr, identical to round 14)
  const int kr = t >> 4;              // 0..15 (+c*16)
  const int kcol = (t & 15) << 3;
  const int vr = t >> 3;              // 0..31 (+c*32)
  const int vcol = (t & 7) << 3;

  bf16x8 ka[4];
  f16x8 va[4];
  f16x8 pa0[4], pa1[4];               // packed P(prev tile) per nq

  // ---- prologue: stage tile 0, load tile 1, S^T(0), exp2, pack ----
#pragma unroll
  for (int c = 0; c < 4; c++)
    ka[c] = *(const bf16x8*)&Kw[(size_t)(kv_base + c * 16 + kr) * DDIM + kcol];
#pragma unroll
  for (int c = 0; c < 4; c++)
    va[c] = *(const f16x8*)&Vtw[(size_t)(c * 32 + vr) * LQ + kv_base + vcol];

#pragma unroll
  for (int c = 0; c < 4; c++)
    *(bf16x8*)&Kl[0][(c * 16 + kr) * 136 + kcol] = ka[c];
#pragma unroll
  for (int c = 0; c < 4; c++)
    *(f16x8*)&Vl[0][(c * 32 + vr) * 72 + vcol] = va[c];

#pragma unroll
  for (int c = 0; c < 4; c++)
    ka[c] = *(const bf16x8*)&Kw[(size_t)(kv_base + 64 + c * 16 + kr) * DDIM + kcol];
#pragma unroll
  for (int c = 0; c < 4; c++)
    va[c] = *(const f16x8*)&Vtw[(size_t)(c * 32 + vr) * LQ + kv_base + 64 + vcol];

  lds_barrier();

  f32x16 s00 = z16, s01 = z16, s10 = z16, s11 = z16;  // [mk][nq]
  __builtin_amdgcn_s_setprio(1);
#pragma unroll
  for (int ks = 0; ks < 8; ks++) {
    bf16x8 kf0 = *(const bf16x8*)&Kl[0][l31 * 136 + ks * 16 + hi * 8];
    bf16x8 kf1 = *(const bf16x8*)&Kl[0][(32 + l31) * 136 + ks * 16 + hi * 8];
    s00 = __builtin_amdgcn_mfma_f32_32x32x16_bf16(kf0, qf0[ks], s00, 0, 0, 0);
    s01 = __builtin_amdgcn_mfma_f32_32x32x16_bf16(kf0, qf1[ks], s01, 0, 0, 0);
    s10 = __builtin_amdgcn_mfma_f32_32x32x16_bf16(kf1, qf0[ks], s10, 0, 0, 0);
    s11 = __builtin_amdgcn_mfma_f32_32x32x16_bf16(kf1, qf1[ks], s11, 0, 0, 0);
  }
  __builtin_amdgcn_s_setprio(0);
#pragma unroll
  for (int r = 0; r < 16; r++) {
    s00[r] = __builtin_amdgcn_exp2f(s00[r]);
    s01[r] = __builtin_amdgcn_exp2f(s01[r]);
    s10[r] = __builtin_amdgcn_exp2f(s10[r]);
    s11[r] = __builtin_amdgcn_exp2f(s11[r]);
  }
#pragma unroll
  for (int sl = 0; sl < 4; sl++) {    // slice = mk*2+h
    const int b = (sl & 1) * 8;
    {
      const f32x16 s = (sl >> 1) ? s10 : s00;   // nq=0
      uint32_t a0 = pkrtz(s[b + 0], s[b + 1]);
      uint32_t a1 = pkrtz(s[b + 2], s[b + 3]);
      uint32_t a2 = pkrtz(s[b + 4], s[b + 5]);
      uint32_t a3 = pkrtz(s[b + 6], s[b + 7]);
      asm("v_permlane32_swap_b32 %0, %1" : "+v"(a0), "+v"(a2));
      asm("v_permlane32_swap_b32 %0, %1" : "+v"(a1), "+v"(a3));
      u32x4 aw; aw.x = a0; aw.y = a1; aw.z = a2; aw.w = a3;
      pa0[sl] = __builtin_bit_cast(f16x8, aw);
    }
    {
      const f32x16 s = (sl >> 1) ? s11 : s01;   // nq=1
      uint32_t a0 = pkrtz(s[b + 0], s[b + 1]);
      uint32_t a1 = pkrtz(s[b + 2], s[b + 3]);
      uint32_t a2 = pkrtz(s[b + 4], s[b + 5]);
      uint32_t a3 = pkrtz(s[b + 6], s[b + 7]);
      asm("v_permlane32_swap_b32 %0, %1" : "+v"(a0), "+v"(a2));
      asm("v_permlane32_swap_b32 %0, %1" : "+v"(a1), "+v"(a3));
      u32x4 aw; aw.x = a0; aw.y = a1; aw.z = a2; aw.w = a3;
      pa1[sl] = __builtin_bit_cast(f16x8, aw);
    }
  }

  // ---- main pipeline: iter t computes S^T(t+1) ZIP PV(t) ----
  for (int tile = 0; tile < 15; tile++) {
    bf16* Kb = Kl[(tile + 1) & 1];
    f16*  Vb = Vl[(tile + 1) & 1];
    f16*  Vp = Vl[tile & 1];
#pragma unroll
    for (int c = 0; c < 4; c++)
      *(bf16x8*)&Kb[(c * 16 + kr) * 136 + kcol] = ka[c];
#pragma unroll
    for (int c = 0; c < 4; c++)
      *(f16x8*)&Vb[(c * 32 + vr) * 72 + vcol] = va[c];

    const int kvn = kv_base + (tile < 14 ? tile + 2 : 15) * 64;
#pragma unroll
    for (int c = 0; c < 4; c++)
      ka[c] = *(const bf16x8*)&Kw[(size_t)(kvn + c * 16 + kr) * DDIM + kcol];
#pragma unroll
    for (int c = 0; c < 4; c++)
      va[c] = *(const f16x8*)&Vtw[(size_t)(c * 32 + vr) * LQ + kvn + vcol];

    lds_barrier();

    // ZIP: S^T(t+1) interleaved with PV(t)+li(t); each kf/vf feeds 2 MFMAs
    s00 = z16; s01 = z16; s10 = z16; s11 = z16;
    __builtin_amdgcn_s_setprio(1);
#pragma unroll
    for (int i = 0; i < 4; i++) {
      bf16x8 kf0a = *(const bf16x8*)&Kb[l31 * 136 + (2 * i) * 16 + hi * 8];
      bf16x8 kf1a = *(const bf16x8*)&Kb[(32 + l31) * 136 + (2 * i) * 16 + hi * 8];
      bf16x8 kf0b = *(const bf16x8*)&Kb[l31 * 136 + (2 * i + 1) * 16 + hi * 8];
      bf16x8 kf1b = *(const bf16x8*)&Kb[(32 + l31) * 136 + (2 * i + 1) * 16 + hi * 8];
      s00 = __builtin_amdgcn_mfma_f32_32x32x16_bf16(kf0a, qf0[2 * i], s00, 0, 0, 0);
      s01 = __builtin_amdgcn_mfma_f32_32x32x16_bf16(kf0a, qf1[2 * i], s01, 0, 0, 0);
      s10 = __builtin_amdgcn_mfma_f32_32x32x16_bf16(kf1a, qf0[2 * i], s10, 0, 0, 0);
      s11 = __builtin_amdgcn_mfma_f32_32x32x16_bf16(kf1a, qf1[2 * i], s11, 0, 0, 0);
      const int koff = (i >> 1) * 32 + (i & 1) * 16 + hi * 8;
#pragma unroll
      for (int dt = 0; dt < 4; dt++) {
        f16x8 vf = *(const f16x8*)&Vp[(dt * 32 + l31) * 72 + koff];
        o0[dt] = __builtin_amdgcn_mfma_f32_32x32x16_f16(pa0[i], vf, o0[dt], 0, 0, 0);
        o1[dt] = __builtin_amdgcn_mfma_f32_32x32x16_f16(pa1[i], vf, o1[dt], 0, 0, 0);
      }
      li0 = __builtin_amdgcn_mfma_f32_32x32x16_f16(pa0[i], ones, li0, 0, 0, 0);
      li1 = __builtin_amdgcn_mfma_f32_32x32x16_f16(pa1[i], ones, li1, 0, 0, 0);
      s00 = __builtin_amdgcn_mfma_f32_32x32x16_bf16(kf0b, qf0[2 * i + 1], s00, 0, 0, 0);
      s01 = __builtin_amdgcn_mfma_f32_32x32x16_bf16(kf0b, qf1[2 * i + 1], s01, 0, 0, 0);
      s10 = __builtin_amdgcn_mfma_f32_32x32x16_bf16(kf1b, qf0[2 * i + 1], s10, 0, 0, 0);
      s11 = __builtin_amdgcn_mfma_f32_32x32x16_bf16(kf1b, qf1[2 * i + 1], s11, 0, 0, 0);
    }
    __builtin_amdgcn_s_setprio(0);

    // exp2(t+1) + pack(t+1) -> pa
#pragma unroll
    for (int r = 0; r < 16; r++) {
      s00[r] = __builtin_amdgcn_exp2f(s00[r]);
      s01[r] = __builtin_amdgcn_exp2f(s01[r]);
      s10[r] = __builtin_amdgcn_exp2f(s10[r]);
      s11[r] = __builtin_amdgcn_exp2f(s11[r]);
    }
#pragma unroll
    for (int sl = 0; sl < 4; sl++) {
      const int b = (sl & 1) * 8;
      {
        const f32x16 s = (sl >> 1) ? s10 : s00;
        uint32_t a0 = pkrtz(s[b + 0], s[b + 1]);
        uint32_t a1 = pkrtz(s[b + 2], s[b + 3]);
        uint32_t a2 = pkrtz(s[b + 4], s[b + 5]);
        uint32_t a3 = pkrtz(s[b + 6], s[b + 7]);
        asm("v_permlane32_swap_b32 %0, %1" : "+v"(a0), "+v"(a2));
        asm("v_permlane32_swap_b32 %0, %1" : "+v"(a1), "+v"(a3));
        u32x4 aw; aw.x = a0; aw.y = a1; aw.z = a2; aw.w = a3;
        pa0[sl] = __builtin_bit_cast(f16x8, aw);
      }
      {
        const f32x16 s = (sl >> 1) ? s11 : s01;
        uint32_t a0 = pkrtz(s[b + 0], s[b + 1]);
        uint32_t a1 = pkrtz(s[b + 2], s[b + 3]);
        uint32_t a2 = pkrtz(s[b + 4], s[b + 5]);
        uint32_t a3 = pkrtz(s[b + 6], s[b + 7]);
        asm("v_permlane32_swap_b32 %0, %1" : "+v"(a0), "+v"(a2));
        asm("v_permlane32_swap_b32 %0, %1" : "+v"(a1), "+v"(a3));
        u32x4 aw; aw.x = a0; aw.y = a1; aw.z = a2; aw.w = a3;
        pa1[sl] = __builtin_bit_cast(f16x8, aw);
      }
    }

    // RACE FIX: iter-t reads of Vl[tile&1] complete before iter-(t+1) staging.
    __builtin_amdgcn_s_barrier();
  }

  // ---- epilogue: PV(15) ----
  {
    f16* Vp = Vl[15 & 1];
    __builtin_amdgcn_s_setprio(1);
#pragma unroll
    for (int i = 0; i < 4; i++) {
      const int koff = (i >> 1) * 32 + (i & 1) * 16 + hi * 8;
#pragma unroll
      for (int dt = 0; dt < 4; dt++) {
        f16x8 vf = *(const f16x8*)&Vp[(dt * 32 + l31) * 72 + koff];
        o0[dt] = __builtin_amdgcn_mfma_f32_32x32x16_f16(pa0[i], vf, o0[dt], 0, 0, 0);
        o1[dt] = __builtin_amdgcn_mfma_f32_32x32x16_f16(pa1[i], vf, o1[dt], 0, 0, 0);
      }
      li0 = __builtin_amdgcn_mfma_f32_32x32x16_f16(pa0[i], ones, li0, 0, 0, 0);
      li1 = __builtin_amdgcn_mfma_f32_32x32x16_f16(pa1[i], ones, li1, 0, 0, 0);
    }
    __builtin_amdgcn_s_setprio(0);
  }

  // epilogue: unnormalized O (bf16) + row sums l
  const size_t po = (size_t)sp * LQ * DDIM;
#pragma unroll
  for (int dt = 0; dt < 4; dt++)
#pragma unroll
    for (int r = 0; r < 16; r++) {
      int crow = (r & 3) + 8 * (r >> 2) + 4 * hi;
      Opb[po + (size_t)(q0w + crow) * DDIM + dt * 32 + l31] = (bf16)o0[dt][r];
      Opb[po + (size_t)(q0w + 32 + crow) * DDIM + dt * 32 + l31] = (bf16)o1[dt][r];
    }
  if (l31 == 0) {
#pragma unroll
    for (int r = 0; r < 16; r++) {
      int crow = (r & 3) + 8 * (r >> 2) + 4 * hi;
      lp[(size_t)sp * LQ + q0w + crow] = li0[r];
      lp[(size_t)sp * LQ + q0w + 32 + crow] = li1[r];
    }
  }
}

// ---------------- K3: combine: out = (sum O_sp) / (sum l_sp) ----------------
__global__ void combine_kernel(const bf16* __restrict__ Opb, const float* __restrict__ lp,
                               float* __restrict__ out) {
  int idx = blockIdx.x * 256 + threadIdx.x;   // LQ * 32
  int q = idx >> 5;
  int d = (idx & 31) * 4;
  float lsum = 0.f;
  float acc[4] = {0.f, 0.f, 0.f, 0.f};
#pragma unroll
  for (int sp = 0; sp < NSPLIT; sp++) {
    lsum += lp[(size_t)sp * LQ + q];
    bf16x4 ov = *(const bf16x4*)&Opb[(size_t)sp * LQ * DDIM + (size_t)q * DDIM + d];
#pragma unroll
    for (int j = 0; j < 4; j++) acc[j] += (float)ov[j];
  }
  float inv = 1.0f / lsum;
  float4 r;
  r.x = acc[0] * inv; r.y = acc[1] * inv; r.z = acc[2] * inv; r.w = acc[3] * inv;
  *(float4*)&out[(size_t)q * DDIM + d] = r;
}

extern "C" void kernel_launch(void* const* d_in, const int* in_sizes, int n_in,
                              void* d_out, int out_size, void* d_ws, size_t ws_size,
                              hipStream_t stream) {
  const float* x  = (const float*)d_in[0];
  const float* Wq = (const float*)d_in[1];
  const float* bq = (const float*)d_in[2];
  const float* Wk = (const float*)d_in[3];
  const float* bk = (const float*)d_in[4];
  const float* Wv = (const float*)d_in[5];
  const float* bv = (const float*)d_in[6];
  char* ws = (char*)d_ws;
  bf16* Qw   = (bf16*)(ws);                              // 4 MB (prescaled by QS)
  bf16* Kw   = (bf16*)(ws + ((size_t)4 << 20));          // 4 MB
  f16*  Vtw  = (f16*)(ws + ((size_t)8 << 20));           // 4 MB (transposed [d][q], f16)
  bf16* Wt   = (bf16*)(ws + ((size_t)12 << 20));         // 768 KB
  float* bias_all = (float*)(ws + ((size_t)12 << 20) + 786432); // 1.5 KB
  bf16* Opb  = (bf16*)(ws + ((size_t)13 << 20));         // 16 MB (4 splits, bf16)
  float* lpp = (float*)(ws + ((size_t)29 << 20));        // 256 KB
  float* out = (float*)d_out;

  prep_kernel<<<1536, 256, 0, stream>>>(Wq, Wk, Wv, bq, bk, bv, Wt, bias_all);
  qkv_gemm<<<256, 512, 0, stream>>>(x, Wt, bias_all, Qw, Kw, Vtw);
  flash_kernel<<<dim3(64, NSPLIT), 256, 0, stream>>>(Qw, Kw, Vtw, Opb, lpp);
  combine_kernel<<<2048, 256, 0, stream>>>(Opb, lpp, out);
}

// Round 16
// 167.243 us; speedup vs baseline: 1.0310x; 1.0310x over previous
//
#include <hip/hip_runtime.h>
#include <stdint.h>

typedef __bf16 bf16;
typedef __bf16 bf16x8 __attribute__((ext_vector_type(8)));
typedef __bf16 bf16x4 __attribute__((ext_vector_type(4)));
typedef _Float16 f16;
typedef f16 f16x8 __attribute__((ext_vector_type(8)));
typedef f16 f16x4 __attribute__((ext_vector_type(4)));
typedef float f32x16 __attribute__((ext_vector_type(16)));
typedef uint32_t u32x4 __attribute__((ext_vector_type(4)));

#define LQ    16384   // B*L total rows
#define CDIM  1024
#define DDIM  128
#define NSPLIT 4
#define QS 0.12751741f   // (1/sqrt(128)) * log2(e): folded into Q -> softmax uses exp2

static __device__ __forceinline__ uint32_t pkrtz(float a, float b) {
  return __builtin_bit_cast(uint32_t, __builtin_amdgcn_cvt_pkrtz(a, b));
}

// no-drain barrier: LDS visibility only; global loads stay in flight.
static __device__ __forceinline__ void lds_barrier() {
  asm volatile("s_waitcnt lgkmcnt(0)" ::: "memory");
  __builtin_amdgcn_s_barrier();
}

// async global->LDS, 16 B per lane; LDS dest = wave-uniform base + lane*16.
static __device__ __forceinline__ void gload_lds16(const void* g, void* l) {
  __builtin_amdgcn_global_load_lds(
      (__attribute__((address_space(1))) void*)g,
      (__attribute__((address_space(3))) void*)l, 16, 0, 0);
}

// ---------------- K0: Wt[3][128][1024] (bf16, Q rows prescaled) + bias_all[384]
__global__ void prep_kernel(const float* __restrict__ Wq, const float* __restrict__ Wk,
                            const float* __restrict__ Wv, const float* __restrict__ bq,
                            const float* __restrict__ bk, const float* __restrict__ bv,
                            bf16* __restrict__ Wt, float* __restrict__ bias_all) {
  int idx = blockIdx.x * 256 + threadIdx.x;      // 0 .. 3*131072
  int p = idx >> 17;
  int rem = idx & 131071;
  int k = rem >> 7, n = rem & 127;
  const float* W = (p == 0) ? Wq : (p == 1) ? Wk : Wv;
  float s = (p == 0) ? QS : 1.0f;
  Wt[(size_t)(p * 128 + n) * CDIM + k] = (bf16)(W[rem] * s);
  if (idx < 384) {
    int pp = idx >> 7, nn = idx & 127;
    const float* b = (pp == 0) ? bq : (pp == 1) ? bk : bv;
    bias_all[idx] = b[nn] * ((pp == 0) ? QS : 1.0f);
  }
}

// ---------------- K1: QKV GEMM, BM=64, BN=384 (all 3 projections per block) --
// grid 256 = 1 block/CU, 512 thr (8 waves, 2m x 4n), wave tile 32x32 x 3 proj.
// B via gload_lds width=16, pre-swizzled source (m97/m173). T4: x prefetched
// 2 steps deep; counted s_waitcnt vmcnt(2) drains B(t+1) while xa(t+2)'s
// 2 dwordx4 loads stay in flight. (round-13 body, measured ~4 us win)
__global__ __launch_bounds__(512, 1) void qkv_gemm(
    const float* __restrict__ x, const bf16* __restrict__ Wt,
    const float* __restrict__ bias_all,
    bf16* __restrict__ Qw, bf16* __restrict__ Kw, f16* __restrict__ Vtw) {
  __shared__ bf16 As[2][64 * 64];    // [m][k] swizzled, 8 KB each
  __shared__ bf16 Bs[2][384 * 64];   // [proj*128+n][k] swizzled, 48 KB each
  const int t = threadIdx.x;
  const int w = t >> 6;
  const int lane = t & 63;
  const int l31 = lane & 31;
  const int hi = lane >> 5;
  const int m0 = blockIdx.x * 64;
  const int m_off = (w & 1) * 32;
  const int n_off = ((w >> 1) & 3) * 32;

  const f32x16 z16 = {0.f,0.f,0.f,0.f,0.f,0.f,0.f,0.f,0.f,0.f,0.f,0.f,0.f,0.f,0.f,0.f};
  f32x16 acc[3];
  acc[0] = z16; acc[1] = z16; acc[2] = z16;

  const int srow = t >> 3;
  const int g = t & 7;
  const int sgoff = (g ^ (srow & 7)) * 8;   // swizzled granule (write side)
  const int scol = g * 8;

  const int lrow = lane >> 3;                 // 0..7
  const int lgr = (lane & 7) ^ lrow;          // pre-swizzled source granule
  const bf16* bsrc = Wt + (size_t)(w * 48 + lrow) * CDIM + lgr * 8;

  float4 xc0, xc1, xn0, xn1;

  // ---- prologue: B(0) async; A(0) staged; xa(1) prefetched ----
#pragma unroll
  for (int c = 0; c < 6; c++)
    gload_lds16(bsrc + (size_t)c * 8 * CDIM, &Bs[0][(w * 48 + c * 8) * 64]);
  {
    const float* p = &x[(size_t)(m0 + srow) * CDIM + scol];
    float4 a0 = *(const float4*)p;
    float4 a1 = *(const float4*)(p + 4);
    bf16x8 v;
    v[0] = (bf16)a0.x; v[1] = (bf16)a0.y; v[2] = (bf16)a0.z; v[3] = (bf16)a0.w;
    v[4] = (bf16)a1.x; v[5] = (bf16)a1.y; v[6] = (bf16)a1.z; v[7] = (bf16)a1.w;
    *(bf16x8*)&As[0][srow * 64 + sgoff] = v;   // implicit vmcnt drains B(0) too
  }
  {
    const float* p = &x[(size_t)(m0 + srow) * CDIM + 64 + scol];
    xc0 = *(const float4*)p;
    xc1 = *(const float4*)(p + 4);
  }
  lds_barrier();   // bar(0)

  for (int kc = 0; kc < 16; kc++) {
    bf16* Ab = As[kc & 1];
    bf16* Bb = Bs[kc & 1];

    if (kc < 15) {
      const bf16* s = bsrc + (kc + 1) * 64;
      bf16* Bn = Bs[(kc + 1) & 1];
#pragma unroll
      for (int c = 0; c < 6; c++)
        gload_lds16(s + (size_t)c * 8 * CDIM, &Bn[(w * 48 + c * 8) * 64]);
      __builtin_amdgcn_sched_barrier(0);   // pin: B issued before xa(t+2)
      if (kc < 14) {
        const float* p = &x[(size_t)(m0 + srow) * CDIM + (kc + 2) * 64 + scol];
        xn0 = *(const float4*)p;
        xn1 = *(const float4*)(p + 4);
      }
    }

#pragma unroll
    for (int ks = 0; ks < 4; ks++) {
      const int rg = ((ks * 2 + hi) ^ (l31 & 7)) * 8;   // swizzled read granule
      bf16x8 af = *(const bf16x8*)&Ab[(m_off + l31) * 64 + rg];
#pragma unroll
      for (int p = 0; p < 3; p++) {
        bf16x8 bfr = *(const bf16x8*)&Bb[(p * 128 + n_off + l31) * 64 + rg];
        acc[p] = __builtin_amdgcn_mfma_f32_32x32x16_bf16(af, bfr, acc[p], 0, 0, 0);
      }
    }

    if (kc < 15) {
      bf16* An = As[(kc + 1) & 1];
      bf16x8 v;
      v[0] = (bf16)xc0.x; v[1] = (bf16)xc0.y; v[2] = (bf16)xc0.z; v[3] = (bf16)xc0.w;
      v[4] = (bf16)xc1.x; v[5] = (bf16)xc1.y; v[6] = (bf16)xc1.z; v[7] = (bf16)xc1.w;
      *(bf16x8*)&An[srow * 64 + sgoff] = v;
      __builtin_amdgcn_sched_barrier(0);
      if (kc < 14)
        asm volatile("s_waitcnt vmcnt(2)" ::: "memory");
      else
        asm volatile("s_waitcnt vmcnt(0)" ::: "memory");
      lds_barrier();   // bar(kc+1): A+B visible
      xc0 = xn0; xc1 = xn1;
    }
  }

  const int n = n_off + l31;
#pragma unroll
  for (int p = 0; p < 3; p++) {
    const float bias = bias_all[p * 128 + n];
    if (p < 2) {
      bf16* outp = (p == 0) ? Qw : Kw;
#pragma unroll
      for (int r = 0; r < 16; r++) {
        int m = m0 + m_off + (r & 3) + 8 * (r >> 2) + 4 * hi;
        outp[(size_t)m * DDIM + n] = (bf16)(acc[p][r] + bias);
      }
    } else {
#pragma unroll
      for (int gq = 0; gq < 4; gq++) {
        int mbase = m0 + m_off + 8 * gq + 4 * hi;
        f16x4 pv;
#pragma unroll
        for (int r = 0; r < 4; r++) pv[r] = (f16)(acc[p][gq * 4 + r] + bias);
        *(f16x4*)&Vtw[(size_t)n * LQ + mbase] = pv;
      }
    }
  }
}

// ---------------- K2: flash attention, pipelined 32x32 MFMA path ------------
// Round-14 green body: 32 q-rows/wave, 2 waves/SIMD (measured optimum of the
// q-row tradeoff — 64q/1wave was -6%, round 15); li via ones-MFMA in the ZIP;
// end-of-body s_barrier race fix.
__global__ __launch_bounds__(256, 2) void flash_kernel(
    const bf16* __restrict__ Qw, const bf16* __restrict__ Kw, const f16* __restrict__ Vtw,
    bf16* __restrict__ Opb, float* __restrict__ lp) {
  __shared__ bf16 Kl[2][64 * 136];    // [kv][d] pad 128->136
  __shared__ f16  Vl[2][128 * 72];    // [d][kv] pad 64->72

  const int t = threadIdx.x;
  const int w = t >> 6;
  const int lane = t & 63;
  const int l31 = lane & 31;
  const int hi = lane >> 5;
  const int lin = blockIdx.y * 128 + blockIdx.x;
  const int logical = ((lin & 7) << 6) + (lin >> 3);
  const int qb = logical & 127;       // 0..127
  const int sp = logical >> 7;        // 0..3
  const int batch = qb >> 5;
  const int q0w = qb * 128 + w * 32;
  const int kv_base = batch * 4096 + sp * 1024;

  bf16x8 qf[8];
#pragma unroll
  for (int ks = 0; ks < 8; ks++)
    qf[ks] = *(const bf16x8*)&Qw[(size_t)(q0w + l31) * DDIM + ks * 16 + hi * 8];

  const f32x16 z16 = {0.f,0.f,0.f,0.f,0.f,0.f,0.f,0.f,0.f,0.f,0.f,0.f,0.f,0.f,0.f,0.f};
  f32x16 o[4];
  o[0] = z16; o[1] = z16; o[2] = z16; o[3] = z16;
  f32x16 liacc = z16;                 // row sums, row q=crow(r,hi)

  f16x8 ones;
#pragma unroll
  for (int i = 0; i < 8; i++) ones[i] = (f16)1.f;

  const int kr = t >> 4;
  const int kcol = (t & 15) << 3;
  const int vr = t >> 3;
  const int vcol = (t & 7) << 3;

  bf16x8 ka[4];
  f16x8 va[4];
  f16x8 pa[4];

#pragma unroll
  for (int c = 0; c < 4; c++)
    ka[c] = *(const bf16x8*)&Kw[(size_t)(kv_base + c * 16 + kr) * DDIM + kcol];
#pragma unroll
  for (int c = 0; c < 4; c++)
    va[c] = *(const f16x8*)&Vtw[(size_t)(c * 32 + vr) * LQ + kv_base + vcol];

#pragma unroll
  for (int c = 0; c < 4; c++)
    *(bf16x8*)&Kl[0][(c * 16 + kr) * 136 + kcol] = ka[c];
#pragma unroll
  for (int c = 0; c < 4; c++)
    *(f16x8*)&Vl[0][(c * 32 + vr) * 72 + vcol] = va[c];

#pragma unroll
  for (int c = 0; c < 4; c++)
    ka[c] = *(const bf16x8*)&Kw[(size_t)(kv_base + 64 + c * 16 + kr) * DDIM + kcol];
#pragma unroll
  for (int c = 0; c < 4; c++)
    va[c] = *(const f16x8*)&Vtw[(size_t)(c * 32 + vr) * LQ + kv_base + 64 + vcol];

  lds_barrier();

  f32x16 sv0 = z16, sv1 = z16;
  __builtin_amdgcn_s_setprio(1);
#pragma unroll
  for (int ks = 0; ks < 8; ks++) {
    bf16x8 kf0 = *(const bf16x8*)&Kl[0][l31 * 136 + ks * 16 + hi * 8];
    bf16x8 kf1 = *(const bf16x8*)&Kl[0][(32 + l31) * 136 + ks * 16 + hi * 8];
    sv0 = __builtin_amdgcn_mfma_f32_32x32x16_bf16(kf0, qf[ks], sv0, 0, 0, 0);
    sv1 = __builtin_amdgcn_mfma_f32_32x32x16_bf16(kf1, qf[ks], sv1, 0, 0, 0);
  }
  __builtin_amdgcn_s_setprio(0);
#pragma unroll
  for (int r = 0; r < 16; r++) {
    sv0[r] = __builtin_amdgcn_exp2f(sv0[r]);
    sv1[r] = __builtin_amdgcn_exp2f(sv1[r]);
  }
#pragma unroll
  for (int sl = 0; sl < 4; sl++) {    // slice = mk*2+h
    const int b = (sl & 1) * 8;
    float s0 = (sl >> 1) ? sv1[b + 0] : sv0[b + 0];
    float s1 = (sl >> 1) ? sv1[b + 1] : sv0[b + 1];
    float s2 = (sl >> 1) ? sv1[b + 2] : sv0[b + 2];
    float s3 = (sl >> 1) ? sv1[b + 3] : sv0[b + 3];
    float s4 = (sl >> 1) ? sv1[b + 4] : sv0[b + 4];
    float s5 = (sl >> 1) ? sv1[b + 5] : sv0[b + 5];
    float s6 = (sl >> 1) ? sv1[b + 6] : sv0[b + 6];
    float s7 = (sl >> 1) ? sv1[b + 7] : sv0[b + 7];
    uint32_t a0 = pkrtz(s0, s1);
    uint32_t a1 = pkrtz(s2, s3);
    uint32_t a2 = pkrtz(s4, s5);
    uint32_t a3 = pkrtz(s6, s7);
    asm("v_permlane32_swap_b32 %0, %1" : "+v"(a0), "+v"(a2));
    asm("v_permlane32_swap_b32 %0, %1" : "+v"(a1), "+v"(a3));
    u32x4 aw; aw.x = a0; aw.y = a1; aw.z = a2; aw.w = a3;
    pa[sl] = __builtin_bit_cast(f16x8, aw);
  }

  for (int tile = 0; tile < 15; tile++) {
    bf16* Kb = Kl[(tile + 1) & 1];
    f16*  Vb = Vl[(tile + 1) & 1];
    f16*  Vp = Vl[tile & 1];
#pragma unroll
    for (int c = 0; c < 4; c++)
      *(bf16x8*)&Kb[(c * 16 + kr) * 136 + kcol] = ka[c];
#pragma unroll
    for (int c = 0; c < 4; c++)
      *(f16x8*)&Vb[(c * 32 + vr) * 72 + vcol] = va[c];

    const int kvn = kv_base + (tile < 14 ? tile + 2 : 15) * 64;
#pragma unroll
    for (int c = 0; c < 4; c++)
      ka[c] = *(const bf16x8*)&Kw[(size_t)(kvn + c * 16 + kr) * DDIM + kcol];
#pragma unroll
    for (int c = 0; c < 4; c++)
      va[c] = *(const f16x8*)&Vtw[(size_t)(c * 32 + vr) * LQ + kvn + vcol];

    lds_barrier();

    // ZIP: S^T(t+1) interleaved with PV(t) + li(t) — independent MFMA chains
    sv0 = z16; sv1 = z16;
    __builtin_amdgcn_s_setprio(1);
#pragma unroll
    for (int i = 0; i < 4; i++) {
      bf16x8 kf0a = *(const bf16x8*)&Kb[l31 * 136 + (2 * i) * 16 + hi * 8];
      bf16x8 kf1a = *(const bf16x8*)&Kb[(32 + l31) * 136 + (2 * i) * 16 + hi * 8];
      bf16x8 kf0b = *(const bf16x8*)&Kb[l31 * 136 + (2 * i + 1) * 16 + hi * 8];
      bf16x8 kf1b = *(const bf16x8*)&Kb[(32 + l31) * 136 + (2 * i + 1) * 16 + hi * 8];
      sv0 = __builtin_amdgcn_mfma_f32_32x32x16_bf16(kf0a, qf[2 * i], sv0, 0, 0, 0);
      sv1 = __builtin_amdgcn_mfma_f32_32x32x16_bf16(kf1a, qf[2 * i], sv1, 0, 0, 0);
      const int koff = (i >> 1) * 32 + (i & 1) * 16 + hi * 8;
#pragma unroll
      for (int dt = 0; dt < 4; dt++) {
        f16x8 vf = *(const f16x8*)&Vp[(dt * 32 + l31) * 72 + koff];
        o[dt] = __builtin_amdgcn_mfma_f32_32x32x16_f16(pa[i], vf, o[dt], 0, 0, 0);
      }
      liacc = __builtin_amdgcn_mfma_f32_32x32x16_f16(pa[i], ones, liacc, 0, 0, 0);
      sv0 = __builtin_amdgcn_mfma_f32_32x32x16_bf16(kf0b, qf[2 * i + 1], sv0, 0, 0, 0);
      sv1 = __builtin_amdgcn_mfma_f32_32x32x16_bf16(kf1b, qf[2 * i + 1], sv1, 0, 0, 0);
    }
    __builtin_amdgcn_s_setprio(0);

    // exp2(t+1) + pack(t+1) -> pa (VALU; overlaps other wave's ZIP)
#pragma unroll
    for (int r = 0; r < 16; r++) {
      sv0[r] = __builtin_amdgcn_exp2f(sv0[r]);
      sv1[r] = __builtin_amdgcn_exp2f(sv1[r]);
    }
#pragma unroll
    for (int sl = 0; sl < 4; sl++) {
      const int b = (sl & 1) * 8;
      float s0 = (sl >> 1) ? sv1[b + 0] : sv0[b + 0];
      float s1 = (sl >> 1) ? sv1[b + 1] : sv0[b + 1];
      float s2 = (sl >> 1) ? sv1[b + 2] : sv0[b + 2];
      float s3 = (sl >> 1) ? sv1[b + 3] : sv0[b + 3];
      float s4 = (sl >> 1) ? sv1[b + 4] : sv0[b + 4];
      float s5 = (sl >> 1) ? sv1[b + 5] : sv0[b + 5];
      float s6 = (sl >> 1) ? sv1[b + 6] : sv0[b + 6];
      float s7 = (sl >> 1) ? sv1[b + 7] : sv0[b + 7];
      uint32_t a0 = pkrtz(s0, s1);
      uint32_t a1 = pkrtz(s2, s3);
      uint32_t a2 = pkrtz(s4, s5);
      uint32_t a3 = pkrtz(s6, s7);
      asm("v_permlane32_swap_b32 %0, %1" : "+v"(a0), "+v"(a2));
      asm("v_permlane32_swap_b32 %0, %1" : "+v"(a1), "+v"(a3));
      u32x4 aw; aw.x = a0; aw.y = a1; aw.z = a2; aw.w = a3;
      pa[sl] = __builtin_bit_cast(f16x8, aw);
    }

    // RACE FIX: iter-t reads of Vl[tile&1] complete before iter-(t+1) staging.
    __builtin_amdgcn_s_barrier();
  }

  {
    f16* Vp = Vl[15 & 1];
    __builtin_amdgcn_s_setprio(1);
#pragma unroll
    for (int i = 0; i < 4; i++) {
      const int koff = (i >> 1) * 32 + (i & 1) * 16 + hi * 8;
#pragma unroll
      for (int dt = 0; dt < 4; dt++) {
        f16x8 vf = *(const f16x8*)&Vp[(dt * 32 + l31) * 72 + koff];
        o[dt] = __builtin_amdgcn_mfma_f32_32x32x16_f16(pa[i], vf, o[dt], 0, 0, 0);
      }
      liacc = __builtin_amdgcn_mfma_f32_32x32x16_f16(pa[i], ones, liacc, 0, 0, 0);
    }
    __builtin_amdgcn_s_setprio(0);
  }

  const size_t po = (size_t)sp * LQ * DDIM;
#pragma unroll
  for (int dt = 0; dt < 4; dt++)
#pragma unroll
    for (int r = 0; r < 16; r++) {
      int q = q0w + (r & 3) + 8 * (r >> 2) + 4 * hi;
      Opb[po + (size_t)q * DDIM + dt * 32 + l31] = (bf16)o[dt][r];
    }
  if (l31 == 0) {
#pragma unroll
    for (int r = 0; r < 16; r++)
      lp[(size_t)sp * LQ + q0w + (r & 3) + 8 * (r >> 2) + 4 * hi] = liacc[r];
  }
}

// ---------------- K3: combine: out = (sum O_sp) / (sum l_sp) ----------------
__global__ void combine_kernel(const bf16* __restrict__ Opb, const float* __restrict__ lp,
                               float* __restrict__ out) {
  int idx = blockIdx.x * 256 + threadIdx.x;   // LQ * 32
  int q = idx >> 5;
  int d = (idx & 31) * 4;
  float lsum = 0.f;
  float acc[4] = {0.f, 0.f, 0.f, 0.f};
#pragma unroll
  for (int sp = 0; sp < NSPLIT; sp++) {
    lsum += lp[(size_t)sp * LQ + q];
    bf16x4 ov = *(const bf16x4*)&Opb[(size_t)sp * LQ * DDIM + (size_t)q * DDIM + d];
#pragma unroll
    for (int j = 0; j < 4; j++) acc[j] += (float)ov[j];
  }
  float inv = 1.0f / lsum;
  float4 r;
  r.x = acc[0] * inv; r.y = acc[1] * inv; r.z = acc[2] * inv; r.w = acc[3] * inv;
  *(float4*)&out[(size_t)q * DDIM + d] = r;
}

extern "C" void kernel_launch(void* const* d_in, const int* in_sizes, int n_in,
                              void* d_out, int out_size, void* d_ws, size_t ws_size,
                              hipStream_t stream) {
  const float* x  = (const float*)d_in[0];
  const float* Wq = (const float*)d_in[1];
  const float* bq = (const float*)d_in[2];
  const float* Wk = (const float*)d_in[3];
  const float* bk = (const float*)d_in[4];
  const float* Wv = (const float*)d_in[5];
  const float* bv = (const float*)d_in[6];
  char* ws = (char*)d_ws;
  bf16* Qw   = (bf16*)(ws);                              // 4 MB (prescaled by QS)
  bf16* Kw   = (bf16*)(ws + ((size_t)4 << 20));          // 4 MB
  f16*  Vtw  = (f16*)(ws + ((size_t)8 << 20));           // 4 MB (transposed [d][q], f16)
  bf16* Wt   = (bf16*)(ws + ((size_t)12 << 20));         // 768 KB
  float* bias_all = (float*)(ws + ((size_t)12 << 20) + 786432); // 1.5 KB
  bf16* Opb  = (bf16*)(ws + ((size_t)13 << 20));         // 16 MB (4 splits, bf16)
  float* lpp = (float*)(ws + ((size_t)29 << 20));        // 256 KB
  float* out = (float*)d_out;

  prep_kernel<<<1536, 256, 0, stream>>>(Wq, Wk, Wv, bq, bk, bv, Wt, bias_all);
  qkv_gemm<<<256, 512, 0, stream>>>(x, Wt, bias_all, Qw, Kw, Vtw);
  flash_kernel<<<dim3(128, NSPLIT), 256, 0, stream>>>(Qw, Kw, Vtw, Opb, lpp);
  combine_kernel<<<2048, 256, 0, stream>>>(Opb, lpp, out);
}